// Round 3
// baseline (876.491 us; speedup 1.0000x reference)
//
#include <hip/hip_runtime.h>

// XTAttention — ROUND 6: proj -> 256^2 deep-pipelined MFMA schedule.
//   BM=BN=256, BK=64, 8 waves (2x4), 512 thr, LDS 128KB (2 slots x 2 halves).
//   Per K-tile: 4 phases {8 ds_read_b128; [q3: stage t+2]; s_barrier;
//   lgkmcnt(0); setprio(1); 16 MFMA; setprio(0); [q3: vmcnt(8)]; s_barrier}.
//   Counted vmcnt keeps 2 K-tiles of loads in flight (never drains to 0 in
//   steady state). T2 granule-XOR swizzle carried from round 5 (conflicts=0).
//   merged aliases Abf so CHB=128 fits when ws allows (proj grid = 1792
//   blocks = exactly 7 full CU rounds).
// attn/final/casts unchanged from round 5 (verified).
// B=128,N=128,D=1024,H=8,HD=128.

typedef unsigned short u16;
typedef __attribute__((ext_vector_type(8))) short bf16x8;  // 8 bf16, 4 VGPR
typedef __attribute__((ext_vector_type(4))) short bf16x4;  // 4 bf16, 2 VGPR
typedef __attribute__((ext_vector_type(4))) float f32x4;

__device__ __forceinline__ float bf2f(u16 x) {
  union { unsigned u; float f; } v;
  v.u = ((unsigned)x) << 16;
  return v.f;
}

__device__ __forceinline__ u16 f2bf(float f) {
  union { float f; unsigned u; } v;
  v.f = f;
  unsigned r = v.u + 0x7fffu + ((v.u >> 16) & 1u);  // RTNE
  return (u16)(r >> 16);
}

__device__ __forceinline__ float ldv(const void* p, size_t i, int f32) {
  return f32 ? ((const float*)p)[i] : bf2f(((const u16*)p)[i]);
}

__device__ __forceinline__ f32x4 MFMA(bf16x8 a, bf16x8 b, f32x4 c) {
  return __builtin_amdgcn_mfma_f32_16x16x32_bf16(a, b, c, 0, 0, 0);
}

#define GLDS16(gp, lp)                                               \
  __builtin_amdgcn_global_load_lds(                                  \
      (const __attribute__((address_space(1))) unsigned int*)(gp),   \
      (__attribute__((address_space(3))) unsigned int*)(lp), 16, 0, 0)

// Swizzled LDS fragment read: logical (row, byte-col) of a [R][64] bf16
// tile stored with LDS[row][x] = G[row][x ^ ((row&7)<<4)] (16B granules).
__device__ __forceinline__ bf16x8 lds_frag(const u16* ls, int row, int cb) {
  const int byte = (row * 128 + cb) ^ ((row & 7) << 4);
  return *(const bf16x8*)((const char*)ls + byte);
}

// ---------------------------------------------------------------------------
// Dtype detection (inputs proved f32 in round 3; keep runtime check).
// ---------------------------------------------------------------------------
__global__ void detect_dtype(const void* words, int* flag) {
  __shared__ int cnt;
  if (threadIdx.x == 0) cnt = 0;
  __syncthreads();
  const u16* w = (const u16*)words;
  int local = 0;
  for (int i = threadIdx.x; i < 2048; i += 256) {
    const u16 v = w[2 * i];
    const int e = (v >> 7) & 0xFF;
    if (v == 0 || (e >= 0x60 && e <= 0x8F)) local++;
  }
  atomicAdd(&cnt, local);
  __syncthreads();
  if (threadIdx.x == 0) *flag = (cnt >= 1434) ? 0 : 1;  // 1 = f32
}

// ---------------------------------------------------------------------------
// Cast + transpose the 8 weight matrices: WT[p][n][k] = W[p][k][n], bf16.
// ---------------------------------------------------------------------------
__global__ __launch_bounds__(256) void cast_w(
    const void* w0, const void* w1, const void* w2, const void* w3,
    const void* w4, const void* w5, const void* w6, const void* w7,
    u16* __restrict__ WT, const int* __restrict__ flag) {
  __shared__ float t[32][33];
  const int f32 = *flag;
  const int p = blockIdx.z;
  const void* W;
  switch (p) {
    case 0: W = w0; break; case 1: W = w1; break; case 2: W = w2; break;
    case 3: W = w3; break; case 4: W = w4; break; case 5: W = w5; break;
    case 6: W = w6; break; default: W = w7; break;
  }
  const int k0 = blockIdx.y * 32, n0 = blockIdx.x * 32;
  const int tx = threadIdx.x & 31, ry = threadIdx.x >> 5;
  for (int r = ry; r < 32; r += 8)
    t[r][tx] = ldv(W, (size_t)(k0 + r) * 1024 + n0 + tx, f32);
  __syncthreads();
  u16* dst = WT + (size_t)p * 1048576ull;
  for (int r = ry; r < 32; r += 8)
    dst[(size_t)(n0 + r) * 1024 + k0 + tx] = f2bf(t[tx][r]);
}

// ---------------------------------------------------------------------------
// Cast activations (chunk rows) to bf16. grid (512,1,3).
// ---------------------------------------------------------------------------
__global__ __launch_bounds__(256) void cast_a(
    const void* x0, const void* x1, const void* x2, u16* __restrict__ Abf,
    int b0, int chb, const int* __restrict__ flag) {
  const int f32 = *flag;
  const int t = blockIdx.z;
  const void* src = (t == 0) ? x0 : ((t == 1) ? x1 : x2);
  u16* dst = Abf + (size_t)t * (size_t)chb * 131072ull;
  const size_t n4 = (size_t)chb * 32768ull;
  const size_t off = (size_t)b0 * 131072ull;
  const size_t stride = (size_t)gridDim.x * 256ull;
  if (f32) {
    const float4* s = (const float4*)src + off / 4;
    for (size_t i = (size_t)blockIdx.x * 256 + threadIdx.x; i < n4; i += stride) {
      const float4 v = s[i];
      bf16x4 o = { (short)f2bf(v.x), (short)f2bf(v.y),
                   (short)f2bf(v.z), (short)f2bf(v.w) };
      *(bf16x4*)&dst[i * 4] = o;
    }
  } else {
    const bf16x4* s = (const bf16x4*)((const u16*)src + off);
    for (size_t i = (size_t)blockIdx.x * 256 + threadIdx.x; i < n4; i += stride)
      ((bf16x4*)dst)[i] = s[i];
  }
}

// ---------------------------------------------------------------------------
// 7 projections, MFMA, 256x256 tile, BK=64, 8 waves, deep pipeline.
// grid (4, CHB/2, 7). Streams 1,2,4,6 stored per-head transposed:
//   T[(b*8+h)*128 + d][j]
// ---------------------------------------------------------------------------
__global__ __launch_bounds__(512, 2) void proj_mfma(
    const u16* __restrict__ Abf, const u16* __restrict__ WT,
    u16* __restrict__ P, int chb) {
  __shared__ u16 lsA[2][2][8192];  // [slot][half][128*64]
  __shared__ u16 lsB[2][2][8192];
  const int p = blockIdx.z;
  const int asel = (p < 3) ? 0 : ((p < 5) ? 1 : 2);
  const u16* A = Abf + (size_t)asel * (size_t)chb * 131072ull;
  const u16* W = WT + (size_t)p * 1048576ull;
  u16* C = P + (size_t)p * (size_t)chb * 131072ull;
  const int tr = (p == 1) | (p == 2) | (p == 4) | (p == 6);

  // XCD-aware bijective remap (nwg divisible by 8 for chb>=4).
  int wg = blockIdx.y * 4 + blockIdx.x;
  const int nwg = (int)gridDim.y * 4;
  if (!(nwg & 7)) wg = (wg & 7) * (nwg >> 3) + (wg >> 3);
  const int bx = wg & 3, by = wg >> 2;
  const int tn = bx * 256, tm = by * 256;

  const int w = threadIdx.x >> 6, l = threadIdx.x & 63;
  const int wm = w >> 2, wn = w & 3;   // 2 x 4 wave grid
  const int lr = l >> 3;               // staging row within 8-row slab
  const int lgr = (l & 7) ^ lr;        // pre-swizzled source 16B-granule
  const int fr = l & 15, fq = l >> 4;  // fragment row / quad
  const int srow0 = w * 16;            // wave's staging row base in a half

  // Stage K-tile kt (all 4 half-tiles) into slot s: 8 gload_lds / thread.
#define STAGE(kt, s)                                                      \
  {                                                                       \
    const int k0 = (kt) * 64 + lgr * 8;                                   \
    _Pragma("unroll")                                                     \
    for (int c = 0; c < 2; ++c) {                                         \
      const int rr = srow0 + c * 8 + lr;                                  \
      GLDS16(&A[(size_t)(tm + rr) * 1024 + k0],                           \
             &lsA[s][0][(srow0 + c * 8) * 64]);                           \
      GLDS16(&A[(size_t)(tm + 128 + rr) * 1024 + k0],                     \
             &lsA[s][1][(srow0 + c * 8) * 64]);                           \
      GLDS16(&W[(size_t)(tn + rr) * 1024 + k0],                           \
             &lsB[s][0][(srow0 + c * 8) * 64]);                           \
      GLDS16(&W[(size_t)(tn + 128 + rr) * 1024 + k0],                     \
             &lsB[s][1][(srow0 + c * 8) * 64]);                           \
    }                                                                     \
  }

  f32x4 acc[8][4] = {};

  // Prologue: stage tiles 0,1; wait tile 0 landed (8 of 16 outstanding).
  STAGE(0, 0);
  STAGE(1, 1);
  asm volatile("s_waitcnt vmcnt(8)" ::: "memory");
  __builtin_amdgcn_s_barrier();

  #pragma unroll 2
  for (int t = 0; t < 16; ++t) {
    const int s = t & 1;
    #pragma unroll
    for (int q = 0; q < 4; ++q) {
      const int mh = q & 1, ks = q >> 1;
      const int cb = ks * 64 + fq * 16;
      bf16x8 af[4], bfr[4];
      #pragma unroll
      for (int m = 0; m < 4; ++m)
        af[m] = lds_frag(&lsA[s][wm][0], mh * 64 + m * 16 + fr, cb);
      #pragma unroll
      for (int n = 0; n < 4; ++n)
        bfr[n] = lds_frag(&lsB[s][wn >> 1][0], (wn & 1) * 64 + n * 16 + fr, cb);
      if (q == 3 && t < 14) STAGE(t + 2, s);
      __builtin_amdgcn_s_barrier();
      asm volatile("s_waitcnt lgkmcnt(0)" ::: "memory");
      __builtin_amdgcn_s_setprio(1);
      #pragma unroll
      for (int m = 0; m < 4; ++m)
        #pragma unroll
        for (int n = 0; n < 4; ++n)
          acc[mh * 4 + m][n] = MFMA(af[m], bfr[n], acc[mh * 4 + m][n]);
      __builtin_amdgcn_s_setprio(0);
      if (q == 3) {
        if (t < 14) asm volatile("s_waitcnt vmcnt(8)" ::: "memory");
        else        asm volatile("s_waitcnt vmcnt(0)" ::: "memory");
      }
      __builtin_amdgcn_s_barrier();
    }
  }
#undef STAGE

  if (!tr) {
    #pragma unroll
    for (int im = 0; im < 8; ++im)
      #pragma unroll
      for (int n = 0; n < 4; ++n) {
        const int row = tm + wm * 128 + (im >> 2) * 64 + (im & 3) * 16 + fq * 4;
        const int col = tn + wn * 64 + n * 16 + fr;
        #pragma unroll
        for (int r = 0; r < 4; ++r)
          C[(size_t)(row + r) * 1024 + col] = f2bf(acc[im][n][r]);
      }
  } else {
    #pragma unroll
    for (int im = 0; im < 8; ++im)
      #pragma unroll
      for (int n = 0; n < 4; ++n) {
        const int grow = tm + wm * 128 + (im >> 2) * 64 + (im & 3) * 16 + fq * 4;
        const int gcol = tn + wn * 64 + n * 16 + fr;
        const int b = grow >> 7, j0 = grow & 127;
        const int h = gcol >> 7, d = gcol & 127;
        const size_t tb = ((size_t)b * 8 + h) * 16384ull;
        bf16x4 v = { (short)f2bf(acc[im][n][0]), (short)f2bf(acc[im][n][1]),
                     (short)f2bf(acc[im][n][2]), (short)f2bf(acc[im][n][3]) };
        *(bf16x4*)&C[tb + (size_t)d * 128 + j0] = v;
      }
  }
}

// ---------------------------------------------------------------------------
// Attention: one block per (b_local, h), 4 waves x 32 rows. (Unchanged.)
// ---------------------------------------------------------------------------
__global__ __launch_bounds__(256) void attn_mfma(
    const u16* __restrict__ P, int chb, u16* __restrict__ merged) {
  __shared__ u16 pl[16384];  // 128x128 bf16, row-swizzled
  const int h = blockIdx.x, b = blockIdx.y;
  const int w = threadIdx.x >> 6, l = threadIdx.x & 63;
  const size_t MS = (size_t)chb * 131072ull;
  const u16* const Qs[3] = { P, P + 3 * MS, P + 5 * MS };
  const u16* const Ks[3] = { P + 1 * MS, P + 4 * MS, P + 6 * MS };
  const u16* V = P + 2 * MS;
  const size_t qb = (size_t)b * 131072ull + (size_t)h * 128;
  const size_t kb = ((size_t)b * 8 + h) * 16384ull;

  f32x4 acc[2][8] = {};
  #pragma unroll
  for (int kt = 0; kt < 128; kt += 32) {
    #pragma unroll
    for (int t = 0; t < 3; ++t) {
      bf16x8 a[2];
      #pragma unroll
      for (int m = 0; m < 2; ++m)
        a[m] = *(const bf16x8*)&Qs[t][qb + (size_t)(w * 32 + m * 16 + (l & 15)) * 1024
                                       + kt + (l >> 4) * 8];
      #pragma unroll
      for (int n = 0; n < 8; ++n) {
        const bf16x8 bb = *(const bf16x8*)&Ks[t][kb + (size_t)(n * 16 + (l & 15)) * 128
                                                 + kt + (l >> 4) * 8];
        acc[0][n] = MFMA(a[0], bb, acc[0][n]);
        acc[1][n] = MFMA(a[1], bb, acc[1][n]);
      }
    }
  }

  const float SC = 0.08838834764831845f;
  #pragma unroll
  for (int m = 0; m < 2; ++m)
    #pragma unroll
    for (int r = 0; r < 4; ++r) {
      float mx = -3.0e38f;
      #pragma unroll
      for (int n = 0; n < 8; ++n) {
        acc[m][n][r] *= SC;
        mx = fmaxf(mx, acc[m][n][r]);
      }
      #pragma unroll
      for (int s = 1; s < 16; s <<= 1) mx = fmaxf(mx, __shfl_xor(mx, s));
      float sm = 0.f;
      #pragma unroll
      for (int n = 0; n < 8; ++n) {
        const float e = __expf(acc[m][n][r] - mx);
        acc[m][n][r] = e;
        sm += e;
      }
      #pragma unroll
      for (int s = 1; s < 16; s <<= 1) sm += __shfl_xor(sm, s);
      const float inv = 1.f / sm;
      #pragma unroll
      for (int n = 0; n < 8; ++n) acc[m][n][r] *= inv;
    }

  #pragma unroll
  for (int m = 0; m < 2; ++m)
    #pragma unroll
    for (int n = 0; n < 8; ++n)
      #pragma unroll
      for (int r = 0; r < 4; ++r) {
        const int row = w * 32 + m * 16 + (l >> 4) * 4 + r;
        const int col = n * 16 + (l & 15);
        const int byte = (row * 256 + col * 2) ^ ((row & 7) << 4);
        *(u16*)((char*)pl + byte) = f2bf(acc[m][n][r]);
      }
  __syncthreads();

  f32x4 o[2][8] = {};
  #pragma unroll
  for (int kt = 0; kt < 128; kt += 32) {
    bf16x8 a[2];
    #pragma unroll
    for (int m = 0; m < 2; ++m) {
      const int row = w * 32 + m * 16 + (l & 15);
      const int byte = (row * 256 + (kt + (l >> 4) * 8) * 2) ^ ((row & 7) << 4);
      a[m] = *(const bf16x8*)((char*)pl + byte);
    }
    #pragma unroll
    for (int n = 0; n < 8; ++n) {
      const bf16x8 bb = *(const bf16x8*)&V[kb + (size_t)(n * 16 + (l & 15)) * 128
                                           + kt + (l >> 4) * 8];
      o[0][n] = MFMA(a[0], bb, o[0][n]);
      o[1][n] = MFMA(a[1], bb, o[1][n]);
    }
  }

  #pragma unroll
  for (int m = 0; m < 2; ++m)
    #pragma unroll
    for (int n = 0; n < 8; ++n)
      #pragma unroll
      for (int r = 0; r < 4; ++r) {
        const int row = w * 32 + m * 16 + (l >> 4) * 4 + r;
        const int col = n * 16 + (l & 15);
        merged[(size_t)(b * 128 + row) * 1024 + h * 128 + col] = f2bf(o[m][n][r]);
      }
}

// ---------------------------------------------------------------------------
// Final projection: out = merged @ Wo + bo. 128^2 BK=64 (round-5 structure).
// ---------------------------------------------------------------------------
__global__ __launch_bounds__(256) void final_mfma(
    const u16* __restrict__ A, const u16* __restrict__ W,
    const void* __restrict__ bias, void* __restrict__ out, int b0,
    const int* __restrict__ flag) {
  __shared__ u16 lsA[128 * 64];
  __shared__ u16 lsB[128 * 64];
  const int f32 = *flag;

  int wg = blockIdx.y * 8 + blockIdx.x;
  const int nwg = (int)gridDim.y * 8;
  wg = (wg & 7) * (nwg >> 3) + (wg >> 3);
  const int bx = wg & 7, by = wg >> 3;

  const int tn = bx * 128;
  const int tm = by * 128;
  const int w = threadIdx.x >> 6, l = threadIdx.x & 63;
  const int wm = w >> 1, wn = w & 1;
  const int lr = l >> 3;
  const int lc = ((l & 7) * 16) ^ (lr << 4);
  const int fr = l & 15, fq = l >> 4;

  f32x4 acc[4][4] = {};
  for (int kt = 0; kt < 1024; kt += 64) {
    #pragma unroll
    for (int c = 0; c < 4; ++c) {
      GLDS16(&A[(size_t)(tm + w * 32 + c * 8 + lr) * 1024 + kt + (lc >> 1)],
             &lsA[(w * 32 + c * 8) * 64]);
      GLDS16(&W[(size_t)(tn + w * 32 + c * 8 + lr) * 1024 + kt + (lc >> 1)],
             &lsB[(w * 32 + c * 8) * 64]);
    }
    __syncthreads();
    #pragma unroll
    for (int ks = 0; ks < 2; ++ks) {
      bf16x8 af[4], bfr[4];
      const int cb = ks * 64 + fq * 16;
      #pragma unroll
      for (int m = 0; m < 4; ++m)
        af[m] = lds_frag(lsA, wm * 64 + m * 16 + fr, cb);
      #pragma unroll
      for (int n = 0; n < 4; ++n)
        bfr[n] = lds_frag(lsB, wn * 64 + n * 16 + fr, cb);
      #pragma unroll
      for (int m = 0; m < 4; ++m)
        #pragma unroll
        for (int n = 0; n < 4; ++n)
          acc[m][n] = MFMA(af[m], bfr[n], acc[m][n]);
    }
    __syncthreads();
  }

  #pragma unroll
  for (int m = 0; m < 4; ++m)
    #pragma unroll
    for (int n = 0; n < 4; ++n)
      #pragma unroll
      for (int r = 0; r < 4; ++r) {
        const int row = tm + wm * 64 + m * 16 + fq * 4 + r;
        const int col = tn + wn * 64 + n * 16 + fr;
        const float rv = acc[m][n][r] + ldv(bias, col, f32);
        const size_t g = (size_t)(b0 * 128 + row) * 1024 + col;
        if (f32) ((float*)out)[g] = rv;
        else ((u16*)out)[g] = f2bf(rv);
      }
}

// ---------------------------------------------------------------------------
extern "C" void kernel_launch(void* const* d_in, const int* in_sizes, int n_in,
                              void* d_out, int out_size, void* d_ws, size_t ws_size,
                              hipStream_t stream) {
  // d_in: 0 words, 1 position, 2 conscious, 3 Wq_w, 4 Wk_w, 5 Wv_w,
  //       6 Wq_p, 7 Wk_p, 8 Wq_c, 9 Wk_c, 10 Wo, 11 bo
  // ws: [flag 64B][WT 8*1M bf16][Abf 3*CHB*128K bf16 (merged aliases Abf)]
  //     [P 7*CHB*128K bf16]
  const size_t fixed = 64ull + 8ull * 1048576ull * 2ull;
  int CHB = 128;
  while (CHB > 2 && fixed + 10ull * (size_t)CHB * 131072ull * 2ull > ws_size)
    CHB >>= 1;

  int* flag = (int*)d_ws;
  u16* WT = (u16*)((char*)d_ws + 64);
  u16* Abf = WT + 8ull * 1048576ull;
  u16* P = Abf + 3ull * (size_t)CHB * 131072ull;
  u16* merged = Abf;  // alias: Abf dead after proj, merged live attn->final

  detect_dtype<<<1, 256, 0, stream>>>(d_in[0], flag);
  cast_w<<<dim3(32, 32, 8), 256, 0, stream>>>(
      d_in[3], d_in[4], d_in[5], d_in[6], d_in[7], d_in[8], d_in[9], d_in[10],
      WT, flag);

  for (int b0 = 0; b0 < 128; b0 += CHB) {
    cast_a<<<dim3(512, 1, 3), 256, 0, stream>>>(
        d_in[0], d_in[1], d_in[2], Abf, b0, CHB, flag);
    proj_mfma<<<dim3(4, CHB / 2, 7), 512, 0, stream>>>(Abf, WT, P, CHB);
    attn_mfma<<<dim3(8, CHB), 256, 0, stream>>>(P, CHB, merged);
    final_mfma<<<dim3(8, CHB), 256, 0, stream>>>(
        merged, WT + 7ull * 1048576ull, d_in[11], d_out, b0, flag);
  }
}

// Round 4
// 729.275 us; speedup vs baseline: 1.2019x; 1.2019x over previous
//
#include <hip/hip_runtime.h>

// XTAttention — ROUND 7: coalesced epilogues everywhere.
// r4/r5/r6 evidence: three different K-loop structures all ~520-570 TF with
// nothing saturated => bottleneck is the 2B/lane scattered C-writes (L2 write
// transactions), common to all. Fix: stage C-tiles in LDS (reusing the 32KB
// staging space after the K-loop), then 16B/lane coalesced global stores.
// K-loop = round-5 verbatim (BK=64, both-sides XOR swizzle, conflict-0,
// XCD-aware bijective block remap). attn core unchanged; its merged-write
// and final's output get the same LDS-stage treatment.
// B=128,N=128,D=1024,H=8,HD=128.

typedef unsigned short u16;
typedef __attribute__((ext_vector_type(8))) short bf16x8;  // 8 bf16, 4 VGPR
typedef __attribute__((ext_vector_type(4))) short bf16x4;  // 4 bf16, 2 VGPR
typedef __attribute__((ext_vector_type(4))) float f32x4;

__device__ __forceinline__ float bf2f(u16 x) {
  union { unsigned u; float f; } v;
  v.u = ((unsigned)x) << 16;
  return v.f;
}

__device__ __forceinline__ u16 f2bf(float f) {
  union { float f; unsigned u; } v;
  v.f = f;
  unsigned r = v.u + 0x7fffu + ((v.u >> 16) & 1u);  // RTNE
  return (u16)(r >> 16);
}

__device__ __forceinline__ float ldv(const void* p, size_t i, int f32) {
  return f32 ? ((const float*)p)[i] : bf2f(((const u16*)p)[i]);
}

__device__ __forceinline__ f32x4 MFMA(bf16x8 a, bf16x8 b, f32x4 c) {
  return __builtin_amdgcn_mfma_f32_16x16x32_bf16(a, b, c, 0, 0, 0);
}

#define GLDS16(gp, lp)                                               \
  __builtin_amdgcn_global_load_lds(                                  \
      (const __attribute__((address_space(1))) unsigned int*)(gp),   \
      (__attribute__((address_space(3))) unsigned int*)(lp), 16, 0, 0)

// Swizzled LDS fragment read: logical (row, byte-col) of a [R][64] bf16
// tile stored with LDS[row][x] = G[row][x ^ ((row&7)<<4)] (16B granules).
__device__ __forceinline__ bf16x8 lds_frag(const u16* ls, int row, int cb) {
  const int byte = (row * 128 + cb) ^ ((row & 7) << 4);
  return *(const bf16x8*)((const char*)ls + byte);
}

// C-stage swizzle for a [128][128] bf16 tile (256B rows): bijective within
// row (XOR touches only col bits 4..6).
__device__ __forceinline__ int cs_byte(int row, int colb) {
  return (row * 256 + colb) ^ ((row & 7) << 4);
}

// ---------------------------------------------------------------------------
// Dtype detection (inputs proved f32 in round 3; keep runtime check).
// ---------------------------------------------------------------------------
__global__ void detect_dtype(const void* words, int* flag) {
  __shared__ int cnt;
  if (threadIdx.x == 0) cnt = 0;
  __syncthreads();
  const u16* w = (const u16*)words;
  int local = 0;
  for (int i = threadIdx.x; i < 2048; i += 256) {
    const u16 v = w[2 * i];
    const int e = (v >> 7) & 0xFF;
    if (v == 0 || (e >= 0x60 && e <= 0x8F)) local++;
  }
  atomicAdd(&cnt, local);
  __syncthreads();
  if (threadIdx.x == 0) *flag = (cnt >= 1434) ? 0 : 1;  // 1 = f32
}

// ---------------------------------------------------------------------------
// Cast + transpose the 8 weight matrices: WT[p][n][k] = W[p][k][n], bf16.
// ---------------------------------------------------------------------------
__global__ __launch_bounds__(256) void cast_w(
    const void* w0, const void* w1, const void* w2, const void* w3,
    const void* w4, const void* w5, const void* w6, const void* w7,
    u16* __restrict__ WT, const int* __restrict__ flag) {
  __shared__ float t[32][33];
  const int f32 = *flag;
  const int p = blockIdx.z;
  const void* W;
  switch (p) {
    case 0: W = w0; break; case 1: W = w1; break; case 2: W = w2; break;
    case 3: W = w3; break; case 4: W = w4; break; case 5: W = w5; break;
    case 6: W = w6; break; default: W = w7; break;
  }
  const int k0 = blockIdx.y * 32, n0 = blockIdx.x * 32;
  const int tx = threadIdx.x & 31, ry = threadIdx.x >> 5;
  for (int r = ry; r < 32; r += 8)
    t[r][tx] = ldv(W, (size_t)(k0 + r) * 1024 + n0 + tx, f32);
  __syncthreads();
  u16* dst = WT + (size_t)p * 1048576ull;
  for (int r = ry; r < 32; r += 8)
    dst[(size_t)(n0 + r) * 1024 + k0 + tx] = f2bf(t[tx][r]);
}

// ---------------------------------------------------------------------------
// Cast activations (chunk rows) to bf16. grid (512,1,3).
// ---------------------------------------------------------------------------
__global__ __launch_bounds__(256) void cast_a(
    const void* x0, const void* x1, const void* x2, u16* __restrict__ Abf,
    int b0, int chb, const int* __restrict__ flag) {
  const int f32 = *flag;
  const int t = blockIdx.z;
  const void* src = (t == 0) ? x0 : ((t == 1) ? x1 : x2);
  u16* dst = Abf + (size_t)t * (size_t)chb * 131072ull;
  const size_t n4 = (size_t)chb * 32768ull;
  const size_t off = (size_t)b0 * 131072ull;
  const size_t stride = (size_t)gridDim.x * 256ull;
  if (f32) {
    const float4* s = (const float4*)src + off / 4;
    for (size_t i = (size_t)blockIdx.x * 256 + threadIdx.x; i < n4; i += stride) {
      const float4 v = s[i];
      bf16x4 o = { (short)f2bf(v.x), (short)f2bf(v.y),
                   (short)f2bf(v.z), (short)f2bf(v.w) };
      *(bf16x4*)&dst[i * 4] = o;
    }
  } else {
    const bf16x4* s = (const bf16x4*)((const u16*)src + off);
    for (size_t i = (size_t)blockIdx.x * 256 + threadIdx.x; i < n4; i += stride)
      ((bf16x4*)dst)[i] = s[i];
  }
}

// ---------------------------------------------------------------------------
// 7 projections, MFMA. 128x128 tile/block, 4 waves (2x2), BK=64.
// K-loop identical to round 5. Epilogue: LDS-stage (reuses the 32KB staging
// space) + 16B/lane coalesced stores. Streams 1,2,4,6 stored per-head
// transposed: T[(b*8+h)*128 + d][j].
// ---------------------------------------------------------------------------
__global__ __launch_bounds__(256) void proj_mfma(
    const u16* __restrict__ Abf, const u16* __restrict__ WT,
    u16* __restrict__ P, int chb) {
  __shared__ u16 lds[16384];  // 32KB: K-loop = lsA|lsB; epilogue = C-stage
  u16* lsA = lds;
  u16* lsB = lds + 8192;
  const int p = blockIdx.z;
  const int asel = (p < 3) ? 0 : ((p < 5) ? 1 : 2);
  const u16* A = Abf + (size_t)asel * (size_t)chb * 131072ull;
  const u16* W = WT + (size_t)p * 1048576ull;
  u16* C = P + (size_t)p * (size_t)chb * 131072ull;
  const int tr = (p == 1) | (p == 2) | (p == 4) | (p == 6);

  // XCD-aware bijective remap (nwg = 8*CHB, divisible by 8).
  int wg = blockIdx.y * 8 + blockIdx.x;
  const int nwg = (int)gridDim.y * 8;
  wg = (wg & 7) * (nwg >> 3) + (wg >> 3);
  const int bx = wg & 7, by = wg >> 3;

  const int tn = bx * 128;
  const int tm = by * 128;
  const int w = threadIdx.x >> 6, l = threadIdx.x & 63;
  const int wm = w >> 1, wn = w & 1;
  const int lr = l >> 3;                              // 0..7
  const int lc = ((l & 7) * 16) ^ (lr << 4);          // byte col, pre-swizzled
  const int fr = l & 15, fq = l >> 4;                 // fragment row/quad

  f32x4 acc[4][4] = {};
  for (int kt = 0; kt < 1024; kt += 64) {
    #pragma unroll
    for (int c = 0; c < 4; ++c) {
      GLDS16(&A[(size_t)(tm + w * 32 + c * 8 + lr) * 1024 + kt + (lc >> 1)],
             &lsA[(w * 32 + c * 8) * 64]);
      GLDS16(&W[(size_t)(tn + w * 32 + c * 8 + lr) * 1024 + kt + (lc >> 1)],
             &lsB[(w * 32 + c * 8) * 64]);
    }
    __syncthreads();
    #pragma unroll
    for (int ks = 0; ks < 2; ++ks) {
      bf16x8 af[4], bfr[4];
      const int cb = ks * 64 + fq * 16;
      #pragma unroll
      for (int m = 0; m < 4; ++m)
        af[m] = lds_frag(lsA, wm * 64 + m * 16 + fr, cb);
      #pragma unroll
      for (int n = 0; n < 4; ++n)
        bfr[n] = lds_frag(lsB, wn * 64 + n * 16 + fr, cb);
      #pragma unroll
      for (int m = 0; m < 4; ++m)
        #pragma unroll
        for (int n = 0; n < 4; ++n)
          acc[m][n] = MFMA(af[m], bfr[n], acc[m][n]);
    }
    __syncthreads();  // also protects lds before epilogue reuse
  }

  // ---- epilogue: stage C tile (transposed for tr streams), coalesced out
  #pragma unroll
  for (int m = 0; m < 4; ++m)
    #pragma unroll
    for (int n = 0; n < 4; ++n)
      #pragma unroll
      for (int r = 0; r < 4; ++r) {
        const int row = wm * 64 + m * 16 + fq * 4 + r;   // local out row
        const int col = wn * 64 + n * 16 + fr;           // local out col
        const int sr = tr ? col : row;                   // staged row
        const int sc = tr ? row : col;                   // staged col
        *(u16*)((char*)lds + cs_byte(sr, sc * 2)) = f2bf(acc[m][n][r]);
      }
  __syncthreads();
  const int crow = threadIdx.x >> 4;            // 0..15
  const int ccb = (threadIdx.x & 15) * 16;      // byte col 0..240
  if (!tr) {
    #pragma unroll
    for (int pass = 0; pass < 8; ++pass) {
      const int row = pass * 16 + crow;
      const bf16x8 v = *(const bf16x8*)((const char*)lds + cs_byte(row, ccb));
      *(bf16x8*)&C[(size_t)(tm + row) * 1024 + tn + (ccb >> 1)] = v;
    }
  } else {
    const size_t tb = ((size_t)by * 8 + bx) * 16384ull;  // (b,h) tile base
    #pragma unroll
    for (int pass = 0; pass < 8; ++pass) {
      const int d = pass * 16 + crow;
      const bf16x8 v = *(const bf16x8*)((const char*)lds + cs_byte(d, ccb));
      *(bf16x8*)&C[tb + (size_t)d * 128 + (ccb >> 1)] = v;
    }
  }
}

// ---------------------------------------------------------------------------
// Attention: one block per (b_local, h), 4 waves x 32 rows. Core unchanged;
// merged-write now LDS-staged + coalesced (reuses pl).
// ---------------------------------------------------------------------------
__global__ __launch_bounds__(256) void attn_mfma(
    const u16* __restrict__ P, int chb, u16* __restrict__ merged) {
  __shared__ u16 pl[16384];  // 128x128 bf16, row-swizzled
  const int h = blockIdx.x, b = blockIdx.y;
  const int w = threadIdx.x >> 6, l = threadIdx.x & 63;
  const size_t MS = (size_t)chb * 131072ull;
  const u16* const Qs[3] = { P, P + 3 * MS, P + 5 * MS };
  const u16* const Ks[3] = { P + 1 * MS, P + 4 * MS, P + 6 * MS };
  const u16* V = P + 2 * MS;
  const size_t qb = (size_t)b * 131072ull + (size_t)h * 128;
  const size_t kb = ((size_t)b * 8 + h) * 16384ull;

  f32x4 acc[2][8] = {};
  #pragma unroll
  for (int kt = 0; kt < 128; kt += 32) {
    #pragma unroll
    for (int t = 0; t < 3; ++t) {
      bf16x8 a[2];
      #pragma unroll
      for (int m = 0; m < 2; ++m)
        a[m] = *(const bf16x8*)&Qs[t][qb + (size_t)(w * 32 + m * 16 + (l & 15)) * 1024
                                       + kt + (l >> 4) * 8];
      #pragma unroll
      for (int n = 0; n < 8; ++n) {
        const bf16x8 bb = *(const bf16x8*)&Ks[t][kb + (size_t)(n * 16 + (l & 15)) * 128
                                                 + kt + (l >> 4) * 8];
        acc[0][n] = MFMA(a[0], bb, acc[0][n]);
        acc[1][n] = MFMA(a[1], bb, acc[1][n]);
      }
    }
  }

  const float SC = 0.08838834764831845f;
  #pragma unroll
  for (int m = 0; m < 2; ++m)
    #pragma unroll
    for (int r = 0; r < 4; ++r) {
      float mx = -3.0e38f;
      #pragma unroll
      for (int n = 0; n < 8; ++n) {
        acc[m][n][r] *= SC;
        mx = fmaxf(mx, acc[m][n][r]);
      }
      #pragma unroll
      for (int s = 1; s < 16; s <<= 1) mx = fmaxf(mx, __shfl_xor(mx, s));
      float sm = 0.f;
      #pragma unroll
      for (int n = 0; n < 8; ++n) {
        const float e = __expf(acc[m][n][r] - mx);
        acc[m][n][r] = e;
        sm += e;
      }
      #pragma unroll
      for (int s = 1; s < 16; s <<= 1) sm += __shfl_xor(sm, s);
      const float inv = 1.f / sm;
      #pragma unroll
      for (int n = 0; n < 8; ++n) acc[m][n][r] *= inv;
    }

  #pragma unroll
  for (int m = 0; m < 2; ++m)
    #pragma unroll
    for (int n = 0; n < 8; ++n)
      #pragma unroll
      for (int r = 0; r < 4; ++r) {
        const int row = w * 32 + m * 16 + (l >> 4) * 4 + r;
        const int col = n * 16 + (l & 15);
        const int byte = (row * 256 + col * 2) ^ ((row & 7) << 4);
        *(u16*)((char*)pl + byte) = f2bf(acc[m][n][r]);
      }
  __syncthreads();

  f32x4 o[2][8] = {};
  #pragma unroll
  for (int kt = 0; kt < 128; kt += 32) {
    bf16x8 a[2];
    #pragma unroll
    for (int m = 0; m < 2; ++m) {
      const int row = w * 32 + m * 16 + (l & 15);
      const int byte = (row * 256 + (kt + (l >> 4) * 8) * 2) ^ ((row & 7) << 4);
      a[m] = *(const bf16x8*)((char*)pl + byte);
    }
    #pragma unroll
    for (int n = 0; n < 8; ++n) {
      const bf16x8 bb = *(const bf16x8*)&V[kb + (size_t)(n * 16 + (l & 15)) * 128
                                           + kt + (l >> 4) * 8];
      o[0][n] = MFMA(a[0], bb, o[0][n]);
      o[1][n] = MFMA(a[1], bb, o[1][n]);
    }
  }

  // ---- merged write: stage into pl (all waves done reading), coalesce out
  __syncthreads();
  #pragma unroll
  for (int m = 0; m < 2; ++m)
    #pragma unroll
    for (int n = 0; n < 8; ++n)
      #pragma unroll
      for (int r = 0; r < 4; ++r) {
        const int row = w * 32 + m * 16 + (l >> 4) * 4 + r;
        const int col = n * 16 + (l & 15);
        *(u16*)((char*)pl + cs_byte(row, col * 2)) = f2bf(o[m][n][r]);
      }
  __syncthreads();
  const int crow = threadIdx.x >> 4;
  const int ccb = (threadIdx.x & 15) * 16;
  #pragma unroll
  for (int pass = 0; pass < 8; ++pass) {
    const int row = pass * 16 + crow;
    const bf16x8 v = *(const bf16x8*)((const char*)pl + cs_byte(row, ccb));
    *(bf16x8*)&merged[(size_t)(b * 128 + row) * 1024 + h * 128 + (ccb >> 1)] = v;
  }
}

// ---------------------------------------------------------------------------
// Final projection: out = merged @ Wo + bo. K-loop = round-5; output staged
// through LDS in two 32KB f32 half-passes, coalesced float4/bf16x4 stores.
// ---------------------------------------------------------------------------
__global__ __launch_bounds__(256) void final_mfma(
    const u16* __restrict__ A, const u16* __restrict__ W,
    const void* __restrict__ bias, void* __restrict__ out, int b0,
    const int* __restrict__ flag) {
  __shared__ u16 lds[16384];  // 32KB: K-loop = lsA|lsB; epilogue = f32 stage
  u16* lsA = lds;
  u16* lsB = lds + 8192;
  const int f32 = *flag;

  int wg = blockIdx.y * 8 + blockIdx.x;
  const int nwg = (int)gridDim.y * 8;
  wg = (wg & 7) * (nwg >> 3) + (wg >> 3);
  const int bx = wg & 7, by = wg >> 3;

  const int tn = bx * 128;
  const int tm = by * 128;
  const int w = threadIdx.x >> 6, l = threadIdx.x & 63;
  const int wm = w >> 1, wn = w & 1;
  const int lr = l >> 3;
  const int lc = ((l & 7) * 16) ^ (lr << 4);
  const int fr = l & 15, fq = l >> 4;

  f32x4 acc[4][4] = {};
  for (int kt = 0; kt < 1024; kt += 64) {
    #pragma unroll
    for (int c = 0; c < 4; ++c) {
      GLDS16(&A[(size_t)(tm + w * 32 + c * 8 + lr) * 1024 + kt + (lc >> 1)],
             &lsA[(w * 32 + c * 8) * 64]);
      GLDS16(&W[(size_t)(tn + w * 32 + c * 8 + lr) * 1024 + kt + (lc >> 1)],
             &lsB[(w * 32 + c * 8) * 64]);
    }
    __syncthreads();
    #pragma unroll
    for (int ks = 0; ks < 2; ++ks) {
      bf16x8 af[4], bfr[4];
      const int cb = ks * 64 + fq * 16;
      #pragma unroll
      for (int m = 0; m < 4; ++m)
        af[m] = lds_frag(lsA, wm * 64 + m * 16 + fr, cb);
      #pragma unroll
      for (int n = 0; n < 4; ++n)
        bfr[n] = lds_frag(lsB, wn * 64 + n * 16 + fr, cb);
      #pragma unroll
      for (int m = 0; m < 4; ++m)
        #pragma unroll
        for (int n = 0; n < 4; ++n)
          acc[m][n] = MFMA(af[m], bfr[n], acc[m][n]);
    }
    __syncthreads();
  }

  // ---- epilogue: two half-passes, f32 staged as [128][64] (32KB)
  float* fs = (float*)lds;
  const int crow = threadIdx.x >> 4;            // 0..15
  const int cq = threadIdx.x & 15;              // 16B column unit
  #pragma unroll
  for (int half = 0; half < 2; ++half) {
    #pragma unroll
    for (int n2 = 0; n2 < 2; ++n2) {
      const int n = half * 2 + n2;
      #pragma unroll
      for (int m = 0; m < 4; ++m)
        #pragma unroll
        for (int r = 0; r < 4; ++r) {
          const int row = wm * 64 + m * 16 + fq * 4 + r;
          const int cpos = wn * 32 + n2 * 16 + fr;   // 0..63 within half
          const int col = tn + wn * 64 + n * 16 + fr;
          const int byte = (row * 256 + cpos * 4) ^ ((row & 7) << 4);
          *(float*)((char*)fs + byte) = acc[m][n][r] + ldv(bias, col, f32);
        }
    }
    __syncthreads();
    #pragma unroll
    for (int pass = 0; pass < 8; ++pass) {
      const int row = pass * 16 + crow;
      const int byte = (row * 256 + cq * 16) ^ ((row & 7) << 4);
      const float4 v = *(const float4*)((const char*)fs + byte);
      const int cpos = cq * 4;                       // 0..60
      const int gcol = tn + (cpos >> 5) * 64 + half * 32 + (cpos & 31);
      const size_t g = (size_t)(b0 * 128 + tm + row) * 1024 + gcol;
      if (f32) {
        *(float4*)&((float*)out)[g] = v;
      } else {
        bf16x4 o = { (short)f2bf(v.x), (short)f2bf(v.y),
                     (short)f2bf(v.z), (short)f2bf(v.w) };
        *(bf16x4*)&((u16*)out)[g] = o;
      }
    }
    __syncthreads();  // protect stage of next half
  }
}

// ---------------------------------------------------------------------------
extern "C" void kernel_launch(void* const* d_in, const int* in_sizes, int n_in,
                              void* d_out, int out_size, void* d_ws, size_t ws_size,
                              hipStream_t stream) {
  // d_in: 0 words, 1 position, 2 conscious, 3 Wq_w, 4 Wk_w, 5 Wv_w,
  //       6 Wq_p, 7 Wk_p, 8 Wq_c, 9 Wk_c, 10 Wo, 11 bo
  // ws: [flag 64B][WT 8*1M bf16][Abf 3*CHB*128K bf16 (merged aliases Abf)]
  //     [P 7*CHB*128K bf16]
  const size_t fixed = 64ull + 8ull * 1048576ull * 2ull;
  int CHB = 128;
  while (CHB > 2 && fixed + 10ull * (size_t)CHB * 131072ull * 2ull > ws_size)
    CHB >>= 1;

  int* flag = (int*)d_ws;
  u16* WT = (u16*)((char*)d_ws + 64);
  u16* Abf = WT + 8ull * 1048576ull;
  u16* P = Abf + 3ull * (size_t)CHB * 131072ull;
  u16* merged = Abf;  // alias: Abf dead after proj, merged live attn->final

  detect_dtype<<<1, 256, 0, stream>>>(d_in[0], flag);
  cast_w<<<dim3(32, 32, 8), 256, 0, stream>>>(
      d_in[3], d_in[4], d_in[5], d_in[6], d_in[7], d_in[8], d_in[9], d_in[10],
      WT, flag);

  for (int b0 = 0; b0 < 128; b0 += CHB) {
    cast_a<<<dim3(512, 1, 3), 256, 0, stream>>>(
        d_in[0], d_in[1], d_in[2], Abf, b0, CHB, flag);
    proj_mfma<<<dim3(8, CHB, 7), 256, 0, stream>>>(Abf, WT, P, CHB);
    attn_mfma<<<dim3(8, CHB), 256, 0, stream>>>(P, CHB, merged);
    final_mfma<<<dim3(8, CHB), 256, 0, stream>>>(
        merged, WT + 7ull * 1048576ull, d_in[11], d_out, b0, flag);
  }
}